// Round 23
// baseline (141.716 us; speedup 1.0000x reference)
//
#include <hip/hip_runtime.h>
#include <hip/hip_bf16.h>
#include <hip/hip_fp16.h>
#include <math.h>

#define M_ROWS 16384
#define DIM 1024

typedef __attribute__((ext_vector_type(8))) short short8;
typedef __attribute__((ext_vector_type(4))) float f32x4;

#define MFMA_BF16(a, b, c) __builtin_amdgcn_mfma_f32_16x16x32_bf16(a, b, c, 0, 0, 0)

#define GLOAD16(gp, lp) __builtin_amdgcn_global_load_lds( \
    (const __attribute__((address_space(1))) unsigned int*)(gp), \
    (__attribute__((address_space(3))) unsigned int*)(lp), 16, 0, 0)

__device__ __forceinline__ short bf16_hi(float x) {
    return (short)__bfloat16_as_ushort(__float2bfloat16(x));
}

__device__ __forceinline__ float fast_asinh(float x) {
    float ax = fabsf(x);
    float r = __logf(ax + sqrtf(fmaf(ax, ax, 1.0f)));
    return copysignf(r, x);
}
__device__ __forceinline__ float fast_sinh(float x) {
    float e = __expf(x), em = __expf(-x);
    return 0.5f * (e - em);
}

// ---- fused prep ----
// blocks [0,2048):    rowprep, 8 rows/block (2 per wave)
// blocks [2048,2304): transpose W -> bf16 Bws (pure transpose)
// blocks [2304,2308): column norms directly from W -> invn (reads-only, no race)
__global__ __launch_bounds__(256) void prep_fused(
    const float* __restrict__ in, const float* __restrict__ W,
    const float* __restrict__ cptr, short* __restrict__ Aws,
    short* __restrict__ Bws, float* __restrict__ cx2,
    float* __restrict__ invn) {
    const int t = threadIdx.x;
    if (blockIdx.x >= 2304) {
        // ---- direct column norm: col-contiguous reads are coalesced ----
        const int col = (blockIdx.x - 2304) * 256 + t;
        float s = 0.f;
#pragma unroll 8
        for (int r = 0; r < DIM; ++r) {
            float v = W[(size_t)r * DIM + col];
            s = fmaf(v, v, s);
        }
        float n = fminf(fmaxf(sqrtf(s), 1e-6f), 1e6f);
        invn[col] = 1.0f / n;
        return;
    }
    if (blockIdx.x >= 2048) {
        // ---- pure transpose W -> Bws[n][k] bf16 ----
        __shared__ float tile[64][65];
        const int b = blockIdx.x - 2048;
        const int k0 = (b >> 4) * 64, n0 = (b & 15) * 64;
        const int rk = t >> 4;
        const int cn = (t & 15) * 4;
#pragma unroll
        for (int p = 0; p < 4; ++p) {
            float4 v = *(const float4*)&W[(size_t)(k0 + rk + p * 16) * DIM + n0 + cn];
            tile[rk + p * 16][cn + 0] = v.x;
            tile[rk + p * 16][cn + 1] = v.y;
            tile[rk + p * 16][cn + 2] = v.z;
            tile[rk + p * 16][cn + 3] = v.w;
        }
        __syncthreads();
        const int rn = t >> 4;
        const int ck = (t & 15) * 4;
#pragma unroll
        for (int p = 0; p < 4; ++p) {
            int n = rn + p * 16;
            union { short s[4]; uint2 u; } ph;
#pragma unroll
            for (int e = 0; e < 4; ++e) ph.s[e] = bf16_hi(tile[ck + e][n]);
            *(uint2*)&Bws[(size_t)(n0 + n) * DIM + k0 + ck] = ph.u;
        }
        return;
    }
    // ---- rowprep (r20-validated): 8 rows/block, 2 per wave ----
    const int w = t >> 6, l = t & 63;
    const int row0 = blockIdx.x * 8 + w * 2;
    const float cc = cptr[0];
    const float rc = sqrtf(cc);
    const float mn = (1.0f - 1e-5f) / rc;

    float4 va[4], vb[4];
    const float4* pa = (const float4*)(in + (size_t)row0 * DIM + l * 16);
    const float4* pb = (const float4*)(in + (size_t)(row0 + 1) * DIM + l * 16);
#pragma unroll
    for (int i = 0; i < 4; ++i) { va[i] = pa[i]; vb[i] = pb[i]; }

#pragma unroll
    for (int rr = 0; rr < 2; ++rr) {
        const int row = row0 + rr;
        float4* v = rr ? vb : va;
        float s = 0.f;
#pragma unroll
        for (int i = 0; i < 4; ++i)
            s += v[i].x * v[i].x + v[i].y * v[i].y + v[i].z * v[i].z + v[i].w * v[i].w;
#pragma unroll
        for (int off = 32; off > 0; off >>= 1) s += __shfl_down(s, off, 64);
        s = __shfl(s, 0, 64);
        float un = sqrtf(fmaxf(s, 1e-15f));
        float xs = tanhf(rc * un) / (rc * un);
        float xn = sqrtf(fmaxf(xs * xs * s, 1e-15f));
        float pf = (xn > mn) ? (mn / xn) : 1.0f;
        float rsv = rc * xs * pf;
        if (l == 0) cx2[row] = rsv * rsv * s;
        union { short sh[8]; uint4 u; } o0, o1;
#pragma unroll
        for (int i = 0; i < 2; ++i) {
            float4 p0 = v[i * 2], p1 = v[i * 2 + 1];
            short* d = i ? o1.sh : o0.sh;
            d[0] = bf16_hi(p0.x * rsv); d[1] = bf16_hi(p0.y * rsv);
            d[2] = bf16_hi(p0.z * rsv); d[3] = bf16_hi(p0.w * rsv);
            d[4] = bf16_hi(p1.x * rsv); d[5] = bf16_hi(p1.y * rsv);
            d[6] = bf16_hi(p1.z * rsv); d[7] = bf16_hi(p1.w * rsv);
        }
        *(uint4*)&Aws[(size_t)row * DIM + l * 16] = o0.u;
        *(uint4*)&Aws[(size_t)row * DIM + l * 16 + 8] = o1.u;
    }
}

// ---- MFMA GEMM: r20 EXACT (validated 55.2 us; constants in epilogue) ----
__global__ __launch_bounds__(512, 2) void gemm_mfma(
    const short* __restrict__ Aws, const short* __restrict__ Bws,
    const float* __restrict__ cx2, const float* __restrict__ invn,
    const float* __restrict__ wg, const float* __restrict__ bias,
    const float* __restrict__ cptr, unsigned short* __restrict__ Yh) {
    __shared__ char smem[163840];

    const int j = blockIdx.x;
    const int wgid = (j & 7) * 32 + (j >> 3);
    const int by = wgid >> 2, bx = wgid & 3;
    const int row0 = by * 256, col0 = bx * 256;

    const int t = threadIdx.x;
    const int l = t & 63, w = t >> 6;
    const int wr = (w >> 2) * 128, wc = (w & 3) * 64;
    const int fr = l & 15, fk3 = l >> 4;

    const int swl = fr >> 1;
    const int pk0 = (fk3 ^ swl) * 8;
    const int pk1 = ((4 | fk3) ^ swl) * 8;

    const int arow0 = (w >> 2) * 128 + (w & 3) * 32;
    const int brow0 = (w & 3) * 64 + (w >> 2) * 32;
    const int lrow8 = l >> 3;
    const int se = ((l & 7) ^ (l >> 4)) * 8;
    const int so = ((l & 7) ^ (4 | (l >> 4))) * 8;
    const size_t gA_base = (size_t)(row0 + arow0 + lrow8) * DIM;
    const size_t gB_base = (size_t)(col0 + brow0 + lrow8) * DIM;
    const int dAoff = arow0 * 64 + l * 8;
    const int dBoff = brow0 * 64 + l * 8;

#define STAGEA(dst, kb) do { \
        GLOAD16(Aws + gA_base +     0 + (kb) + se, (dst) + dAoff);        \
        GLOAD16(Aws + gA_base +  8192 + (kb) + so, (dst) + dAoff + 512);  \
        GLOAD16(Aws + gA_base + 16384 + (kb) + se, (dst) + dAoff + 1024); \
        GLOAD16(Aws + gA_base + 24576 + (kb) + so, (dst) + dAoff + 1536); \
    } while (0)
#define STAGEB(dst, kb) do { \
        GLOAD16(Bws + gB_base +     0 + (kb) + se, (dst) + dBoff);        \
        GLOAD16(Bws + gB_base +  8192 + (kb) + so, (dst) + dBoff + 512);  \
        GLOAD16(Bws + gB_base + 16384 + (kb) + se, (dst) + dBoff + 1024); \
        GLOAD16(Bws + gB_base + 24576 + (kb) + so, (dst) + dBoff + 1536); \
    } while (0)

    f32x4 acc[8][4] = {};

    STAGEB((short*)(smem + 98304), 0);
    STAGEA((short*)smem, 0);
    STAGEA((short*)(smem + 32768), 64);
    asm volatile("s_waitcnt vmcnt(0)" ::: "memory");

#pragma unroll
    for (int s = 0; s < 16; ++s) {
        const short* sA = (const short*)(smem + (s % 3) * 32768);
        const short* sB = (const short*)(smem + 98304 + (s & 1) * 32768);

        __builtin_amdgcn_s_barrier();
        asm volatile("" ::: "memory");

        if (s < 15) STAGEB((short*)(smem + 98304 + ((s + 1) & 1) * 32768),
                           (size_t)(s + 1) * 64);
        if (s < 14) STAGEA((short*)(smem + ((s + 2) % 3) * 32768),
                           (size_t)(s + 2) * 64);

        short8 af[8], bq[4];
#pragma unroll
        for (int n = 0; n < 4; ++n)
            bq[n] = *(const short8*)&sB[(wc + n * 16 + fr) * 64 + pk0];
#pragma unroll
        for (int ig = 0; ig < 8; ++ig)
            af[ig] = *(const short8*)&sA[(wr + ig * 16 + fr) * 64 + pk0];
        __builtin_amdgcn_s_setprio(1);
#pragma unroll
        for (int ig = 0; ig < 8; ++ig)
#pragma unroll
            for (int n = 0; n < 4; ++n)
                acc[ig][n] = MFMA_BF16(af[ig], bq[n], acc[ig][n]);
        __builtin_amdgcn_s_setprio(0);
#pragma unroll
        for (int n = 0; n < 4; ++n)
            bq[n] = *(const short8*)&sB[(wc + n * 16 + fr) * 64 + pk1];
#pragma unroll
        for (int ig = 0; ig < 8; ++ig)
            af[ig] = *(const short8*)&sA[(wr + ig * 16 + fr) * 64 + pk1];
        __builtin_amdgcn_s_setprio(1);
#pragma unroll
        for (int ig = 0; ig < 8; ++ig)
#pragma unroll
            for (int n = 0; n < 4; ++n)
                acc[ig][n] = MFMA_BF16(af[ig], bq[n], acc[ig][n]);
        __builtin_amdgcn_s_setprio(0);

        if (s < 14) asm volatile("s_waitcnt vmcnt(4)" ::: "memory");
        else        asm volatile("s_waitcnt vmcnt(0)" ::: "memory");
    }
#undef STAGEA
#undef STAGEB

    __builtin_amdgcn_s_barrier();

    const float cv = cptr[0];
    const float rcv = sqrtf(cv);
    const float inv_rc = 1.0f / rcv;
    const int fc = l & 15, fq = (l >> 4) * 4;

    float chf[4], shf[4], wff[4];
#pragma unroll
    for (int n = 0; n < 4; ++n) {
        const int col = col0 + wc + n * 16 + fc;
        float dr = 2.0f * rcv * bias[col];
        chf[n] = coshf(dr) * 2.0f * invn[col];
        shf[n] = sinhf(dr);
        wff[n] = 2.0f * wg[col] * inv_rc;
    }

    float* slab = (float*)(smem + 98304 + w * 8192);
    const int rr = l >> 4;
    const int rc16 = l & 15;

#pragma unroll
    for (int i = 0; i < 8; ++i) {
        float cxr[4];
#pragma unroll
        for (int q = 0; q < 4; ++q)
            cxr[q] = cx2[row0 + wr + i * 16 + fq + q];
#pragma unroll
        for (int n = 0; n < 4; ++n)
#pragma unroll
            for (int q = 0; q < 4; ++q) {
                float a = acc[i][n][q];
                float mlr = fmaf(a, chf[n], -(1.0f + cxr[q]) * shf[n]);
                float wv = wff[n] * fast_asinh(mlr);
                slab[(fq + q) * 68 + n * 16 + fc] = fast_sinh(rcv * wv) * inv_rc;
            }
#pragma unroll
        for (int p = 0; p < 4; ++p) {
            float4 v4 = *(const float4*)&slab[(p * 4 + rr) * 68 + rc16 * 4];
            union { unsigned short us[4]; uint2 u; } ho;
            ho.us[0] = __half_as_ushort(__float2half(v4.x));
            ho.us[1] = __half_as_ushort(__float2half(v4.y));
            ho.us[2] = __half_as_ushort(__float2half(v4.z));
            ho.us[3] = __half_as_ushort(__float2half(v4.w));
            *(uint2*)&Yh[(size_t)(row0 + wr + i * 16 + p * 4 + rr) * DIM +
                         col0 + wc + rc16 * 4] = ho.u;
        }
    }
}

// ---- wave-per-row finalize (r20-validated): 8 rows/block, 2 per wave ----
__global__ __launch_bounds__(256) void finalize_h(
    const unsigned short* __restrict__ Yh, float* __restrict__ out,
    const float* __restrict__ cptr) {
    const int t = threadIdx.x;
    const int w = t >> 6, l = t & 63;
    const int row0 = blockIdx.x * 8 + w * 2;
    const float c = cptr[0];
    const float rc = sqrtf(c);
    const float maxnorm = (1.0f - 1e-5f) / rc;

    uint4 ha[2], hb[2];
    const uint4* pa = (const uint4*)(Yh + (size_t)row0 * DIM + l * 16);
    const uint4* pb = (const uint4*)(Yh + (size_t)(row0 + 1) * DIM + l * 16);
#pragma unroll
    for (int i = 0; i < 2; ++i) { ha[i] = pa[i]; hb[i] = pb[i]; }

#pragma unroll
    for (int rr = 0; rr < 2; ++rr) {
        const int row = row0 + rr;
        uint4* hv = rr ? hb : ha;
        float y[16];
#pragma unroll
        for (int i = 0; i < 2; ++i) {
            const unsigned int* u = (const unsigned int*)&hv[i];
#pragma unroll
            for (int k = 0; k < 4; ++k) {
                y[i * 8 + k * 2]     = __half2float(__ushort_as_half((unsigned short)(u[k] & 0xffff)));
                y[i * 8 + k * 2 + 1] = __half2float(__ushort_as_half((unsigned short)(u[k] >> 16)));
            }
        }
        float s1 = 0.f, s2 = 0.f;
        float r[16];
#pragma unroll
        for (int k = 0; k < 16; ++k) {
            s1 = fmaf(y[k], y[k], s1);
            r[k] = fmaxf(y[k], 0.f);
            s2 = fmaf(r[k], r[k], s2);
        }
#pragma unroll
        for (int off = 32; off > 0; off >>= 1) {
            s1 += __shfl_down(s1, off, 64);
            s2 += __shfl_down(s2, off, 64);
        }
        s1 = __shfl(s1, 0, 64);
        s2 = __shfl(s2, 0, 64);

        float g = 1.0f / (1.0f + sqrtf(1.0f + c * s1));
        float xn = sqrtf(fmaxf(g * g * s1, 1e-15f));
        float arg = fminf(rc * xn, 1.0f - 1e-7f);
        float f1 = atanhf(arg) / (rc * xn);
        float fv = f1 * g;
        float vn = sqrtf(fmaxf(fv * fv * s2, 1e-15f));
        float f2 = tanhf(rc * vn) / (rc * vn);
        float en = sqrtf(fmaxf(f2 * f2 * fv * fv * s2, 1e-15f));
        float pf = (en > maxnorm) ? (maxnorm / en) : 1.0f;
        float zn = sqrtf(fmaxf(pf * pf * f2 * f2 * fv * fv * s2, 1e-15f));
        float arg2 = fminf(rc * zn, 1.0f - 1e-7f);
        float f3 = atanhf(arg2) / (rc * zn);
        float F = f3 * pf * f2 * fv;

        float* op = out + (size_t)row * DIM + l * 16;
#pragma unroll
        for (int i = 0; i < 4; ++i) {
            float4 o = make_float4(F * r[i * 4], F * r[i * 4 + 1],
                                   F * r[i * 4 + 2], F * r[i * 4 + 3]);
            *(float4*)(op + i * 4) = o;
        }
    }
}

extern "C" void kernel_launch(void* const* d_in, const int* in_sizes, int n_in,
                              void* d_out, int out_size, void* d_ws, size_t ws_size,
                              hipStream_t stream) {
    const float* inputs   = (const float*)d_in[0];
    const float* weigh_v  = (const float*)d_in[1];
    const float* weight_g = (const float*)d_in[2];
    const float* bias     = (const float*)d_in[3];
    const float* cptr     = (const float*)d_in[4];
    float* out = (float*)d_out;

    // workspace layout (~66.2 MB)
    char* ws = (char*)d_ws;
    short* Aws = (short*)ws;                                       // 32 MB
    short* Bws = (short*)(ws + (size_t)32 * 1024 * 1024);          // 2 MB
    unsigned short* Yh = (unsigned short*)(ws + (size_t)34 * 1024 * 1024); // 32 MB
    float* cx2  = (float*)(ws + (size_t)66 * 1024 * 1024);         // 64 KB
    float* invn = (float*)(ws + (size_t)66 * 1024 * 1024 + 65536); // 4 KB

    prep_fused<<<2048 + 256 + 4, 256, 0, stream>>>(inputs, weigh_v, cptr,
                                                   Aws, Bws, cx2, invn);
    gemm_mfma<<<256, 512, 0, stream>>>(Aws, Bws, cx2, invn,
                                       weight_g, bias, cptr, Yh);
    finalize_h<<<2048, 256, 0, stream>>>(Yh, out, cptr);
}

// Round 24
// 95.651 us; speedup vs baseline: 1.4816x; 1.4816x over previous
//
#include <hip/hip_runtime.h>
#include <hip/hip_bf16.h>
#include <hip/hip_fp16.h>
#include <math.h>

#define M_ROWS 16384
#define DIM 1024

typedef __attribute__((ext_vector_type(8))) short short8;
typedef __attribute__((ext_vector_type(4))) float f32x4;

#define MFMA_BF16(a, b, c) __builtin_amdgcn_mfma_f32_16x16x32_bf16(a, b, c, 0, 0, 0)

#define GLOAD16(gp, lp) __builtin_amdgcn_global_load_lds( \
    (const __attribute__((address_space(1))) unsigned int*)(gp), \
    (__attribute__((address_space(3))) unsigned int*)(lp), 16, 0, 0)

__device__ __forceinline__ short bf16_hi(float x) {
    return (short)__bfloat16_as_ushort(__float2bfloat16(x));
}

__device__ __forceinline__ float fast_asinh(float x) {
    float ax = fabsf(x);
    float r = __logf(ax + sqrtf(fmaf(ax, ax, 1.0f)));
    return copysignf(r, x);
}
__device__ __forceinline__ float fast_sinh(float x) {
    float e = __expf(x), em = __expf(-x);
    return 0.5f * (e - em);
}

// ---- fused prep (r21-exact): blocks 0..2047 rowprep (8 rows each);
//      blocks 2048..2303 transpose W -> bf16 Bws + colnorm partials ----
__global__ __launch_bounds__(256) void prep_fused(
    const float* __restrict__ in, const float* __restrict__ W,
    const float* __restrict__ cptr, short* __restrict__ Aws,
    short* __restrict__ Bws, float* __restrict__ cx2,
    float* __restrict__ part) {
    const int t = threadIdx.x;
    if (blockIdx.x >= 2048) {
        __shared__ float tile[64][65];
        __shared__ float cred[4][64];
        const int b = blockIdx.x - 2048;
        const int k0 = (b >> 4) * 64, n0 = (b & 15) * 64;
        const int rk = t >> 4;
        const int cn = (t & 15) * 4;
#pragma unroll
        for (int p = 0; p < 4; ++p) {
            float4 v = *(const float4*)&W[(size_t)(k0 + rk + p * 16) * DIM + n0 + cn];
            tile[rk + p * 16][cn + 0] = v.x;
            tile[rk + p * 16][cn + 1] = v.y;
            tile[rk + p * 16][cn + 2] = v.z;
            tile[rk + p * 16][cn + 3] = v.w;
        }
        __syncthreads();
        {
            const int c = t & 63, q = t >> 6;
            float s = 0.f;
#pragma unroll
            for (int i = 0; i < 16; ++i) {
                float v = tile[q * 16 + i][c];
                s = fmaf(v, v, s);
            }
            cred[q][c] = s;
        }
        const int rn = t >> 4;
        const int ck = (t & 15) * 4;
#pragma unroll
        for (int p = 0; p < 4; ++p) {
            int n = rn + p * 16;
            union { short s[4]; uint2 u; } ph;
#pragma unroll
            for (int e = 0; e < 4; ++e) ph.s[e] = bf16_hi(tile[ck + e][n]);
            *(uint2*)&Bws[(size_t)(n0 + n) * DIM + k0 + ck] = ph.u;
        }
        __syncthreads();
        if (t < 64)
            part[(size_t)(b >> 4) * 1024 + n0 + t] =
                cred[0][t] + cred[1][t] + cred[2][t] + cred[3][t];
        return;
    }
    const int w = t >> 6, l = t & 63;
    const int row0 = blockIdx.x * 8 + w * 2;
    const float cc = cptr[0];
    const float rc = sqrtf(cc);
    const float mn = (1.0f - 1e-5f) / rc;

    float4 va[4], vb[4];
    const float4* pa = (const float4*)(in + (size_t)row0 * DIM + l * 16);
    const float4* pb = (const float4*)(in + (size_t)(row0 + 1) * DIM + l * 16);
#pragma unroll
    for (int i = 0; i < 4; ++i) { va[i] = pa[i]; vb[i] = pb[i]; }

#pragma unroll
    for (int rr = 0; rr < 2; ++rr) {
        const int row = row0 + rr;
        float4* v = rr ? vb : va;
        float s = 0.f;
#pragma unroll
        for (int i = 0; i < 4; ++i)
            s += v[i].x * v[i].x + v[i].y * v[i].y + v[i].z * v[i].z + v[i].w * v[i].w;
#pragma unroll
        for (int off = 32; off > 0; off >>= 1) s += __shfl_down(s, off, 64);
        s = __shfl(s, 0, 64);
        float un = sqrtf(fmaxf(s, 1e-15f));
        float xs = tanhf(rc * un) / (rc * un);
        float xn = sqrtf(fmaxf(xs * xs * s, 1e-15f));
        float pf = (xn > mn) ? (mn / xn) : 1.0f;
        float rsv = rc * xs * pf;
        if (l == 0) cx2[row] = rsv * rsv * s;
        union { short sh[8]; uint4 u; } o0, o1;
#pragma unroll
        for (int i = 0; i < 2; ++i) {
            float4 p0 = v[i * 2], p1 = v[i * 2 + 1];
            short* d = i ? o1.sh : o0.sh;
            d[0] = bf16_hi(p0.x * rsv); d[1] = bf16_hi(p0.y * rsv);
            d[2] = bf16_hi(p0.z * rsv); d[3] = bf16_hi(p0.w * rsv);
            d[4] = bf16_hi(p1.x * rsv); d[5] = bf16_hi(p1.y * rsv);
            d[6] = bf16_hi(p1.z * rsv); d[7] = bf16_hi(p1.w * rsv);
        }
        *(uint4*)&Aws[(size_t)row * DIM + l * 16] = o0.u;
        *(uint4*)&Aws[(size_t)row * DIM + l * 16 + 8] = o1.u;
    }
}

// ---- MFMA GEMM: r13/r20 EXACT K-loop; epilogue constants via own-column
//      compute + shfl exchange (4x less serial head work than r21) ----
__global__ __launch_bounds__(512, 2) void gemm_mfma(
    const short* __restrict__ Aws, const short* __restrict__ Bws,
    const float* __restrict__ cx2, const float* __restrict__ part,
    const float* __restrict__ wg, const float* __restrict__ bias,
    const float* __restrict__ cptr, unsigned short* __restrict__ Yh) {
    __shared__ char smem[163840];

    const int j = blockIdx.x;
    const int wgid = (j & 7) * 32 + (j >> 3);
    const int by = wgid >> 2, bx = wgid & 3;
    const int row0 = by * 256, col0 = bx * 256;

    const int t = threadIdx.x;
    const int l = t & 63, w = t >> 6;
    const int wr = (w >> 2) * 128, wc = (w & 3) * 64;
    const int fr = l & 15, fk3 = l >> 4;

    const int swl = fr >> 1;
    const int pk0 = (fk3 ^ swl) * 8;
    const int pk1 = ((4 | fk3) ^ swl) * 8;

    const int arow0 = (w >> 2) * 128 + (w & 3) * 32;
    const int brow0 = (w & 3) * 64 + (w >> 2) * 32;
    const int lrow8 = l >> 3;
    const int se = ((l & 7) ^ (l >> 4)) * 8;
    const int so = ((l & 7) ^ (4 | (l >> 4))) * 8;
    const size_t gA_base = (size_t)(row0 + arow0 + lrow8) * DIM;
    const size_t gB_base = (size_t)(col0 + brow0 + lrow8) * DIM;
    const int dAoff = arow0 * 64 + l * 8;
    const int dBoff = brow0 * 64 + l * 8;

#define STAGEA(dst, kb) do { \
        GLOAD16(Aws + gA_base +     0 + (kb) + se, (dst) + dAoff);        \
        GLOAD16(Aws + gA_base +  8192 + (kb) + so, (dst) + dAoff + 512);  \
        GLOAD16(Aws + gA_base + 16384 + (kb) + se, (dst) + dAoff + 1024); \
        GLOAD16(Aws + gA_base + 24576 + (kb) + so, (dst) + dAoff + 1536); \
    } while (0)
#define STAGEB(dst, kb) do { \
        GLOAD16(Bws + gB_base +     0 + (kb) + se, (dst) + dBoff);        \
        GLOAD16(Bws + gB_base +  8192 + (kb) + so, (dst) + dBoff + 512);  \
        GLOAD16(Bws + gB_base + 16384 + (kb) + se, (dst) + dBoff + 1024); \
        GLOAD16(Bws + gB_base + 24576 + (kb) + so, (dst) + dBoff + 1536); \
    } while (0)

    f32x4 acc[8][4] = {};

    STAGEB((short*)(smem + 98304), 0);
    STAGEA((short*)smem, 0);
    STAGEA((short*)(smem + 32768), 64);
    asm volatile("s_waitcnt vmcnt(0)" ::: "memory");

#pragma unroll
    for (int s = 0; s < 16; ++s) {
        const short* sA = (const short*)(smem + (s % 3) * 32768);
        const short* sB = (const short*)(smem + 98304 + (s & 1) * 32768);

        __builtin_amdgcn_s_barrier();
        asm volatile("" ::: "memory");

        if (s < 15) STAGEB((short*)(smem + 98304 + ((s + 1) & 1) * 32768),
                           (size_t)(s + 1) * 64);
        if (s < 14) STAGEA((short*)(smem + ((s + 2) % 3) * 32768),
                           (size_t)(s + 2) * 64);

        short8 af[8], bq[4];
#pragma unroll
        for (int n = 0; n < 4; ++n)
            bq[n] = *(const short8*)&sB[(wc + n * 16 + fr) * 64 + pk0];
#pragma unroll
        for (int ig = 0; ig < 8; ++ig)
            af[ig] = *(const short8*)&sA[(wr + ig * 16 + fr) * 64 + pk0];
        __builtin_amdgcn_s_setprio(1);
#pragma unroll
        for (int ig = 0; ig < 8; ++ig)
#pragma unroll
            for (int n = 0; n < 4; ++n)
                acc[ig][n] = MFMA_BF16(af[ig], bq[n], acc[ig][n]);
        __builtin_amdgcn_s_setprio(0);
#pragma unroll
        for (int n = 0; n < 4; ++n)
            bq[n] = *(const short8*)&sB[(wc + n * 16 + fr) * 64 + pk1];
#pragma unroll
        for (int ig = 0; ig < 8; ++ig)
            af[ig] = *(const short8*)&sA[(wr + ig * 16 + fr) * 64 + pk1];
        __builtin_amdgcn_s_setprio(1);
#pragma unroll
        for (int ig = 0; ig < 8; ++ig)
#pragma unroll
            for (int n = 0; n < 4; ++n)
                acc[ig][n] = MFMA_BF16(af[ig], bq[n], acc[ig][n]);
        __builtin_amdgcn_s_setprio(0);

        if (s < 14) asm volatile("s_waitcnt vmcnt(4)" ::: "memory");
        else        asm volatile("s_waitcnt vmcnt(0)" ::: "memory");
    }
#undef STAGEA
#undef STAGEB

    __builtin_amdgcn_s_barrier();

    const float cv = cptr[0];
    const float rcv = sqrtf(cv);
    const float inv_rc = 1.0f / rcv;
    const int fc = l & 15, fq = (l >> 4) * 4;

    // each lane computes constants for its OWN column (n_own = l>>4),
    // then exchanges across the 4 fq-groups via shfl (lane (n<<4)|fc).
    float chf[4], shf[4], wff[4];
    {
        const int col_own = col0 + wc + (l >> 4) * 16 + fc;
        float ssum = 0.f;
#pragma unroll
        for (int p = 0; p < 16; ++p) ssum += part[(size_t)p * 1024 + col_own];
        float nrm = fminf(fmaxf(sqrtf(ssum), 1e-6f), 1e6f);
        float invn_own = 1.0f / nrm;
        float dr = 2.0f * rcv * bias[col_own];
        float chf_own = coshf(dr) * 2.0f * invn_own;
        float shf_own = sinhf(dr);
        float wff_own = 2.0f * wg[col_own] * inv_rc;
#pragma unroll
        for (int n = 0; n < 4; ++n) {
            int src = (n << 4) | fc;
            chf[n] = __shfl(chf_own, src, 64);
            shf[n] = __shfl(shf_own, src, 64);
            wff[n] = __shfl(wff_own, src, 64);
        }
    }

    float* slab = (float*)(smem + 98304 + w * 8192);
    const int rr = l >> 4;
    const int rc16 = l & 15;

#pragma unroll
    for (int i = 0; i < 8; ++i) {
        float cxr[4];
#pragma unroll
        for (int q = 0; q < 4; ++q)
            cxr[q] = cx2[row0 + wr + i * 16 + fq + q];
#pragma unroll
        for (int n = 0; n < 4; ++n)
#pragma unroll
            for (int q = 0; q < 4; ++q) {
                float a = acc[i][n][q];
                float mlr = fmaf(a, chf[n], -(1.0f + cxr[q]) * shf[n]);
                float wv = wff[n] * fast_asinh(mlr);
                slab[(fq + q) * 68 + n * 16 + fc] = fast_sinh(rcv * wv) * inv_rc;
            }
#pragma unroll
        for (int p = 0; p < 4; ++p) {
            float4 v4 = *(const float4*)&slab[(p * 4 + rr) * 68 + rc16 * 4];
            union { unsigned short us[4]; uint2 u; } ho;
            ho.us[0] = __half_as_ushort(__float2half(v4.x));
            ho.us[1] = __half_as_ushort(__float2half(v4.y));
            ho.us[2] = __half_as_ushort(__float2half(v4.z));
            ho.us[3] = __half_as_ushort(__float2half(v4.w));
            *(uint2*)&Yh[(size_t)(row0 + wr + i * 16 + p * 4 + rr) * DIM +
                         col0 + wc + rc16 * 4] = ho.u;
        }
    }
}

// ---- wave-per-row finalize (r20-validated): 8 rows/block, 2 per wave ----
__global__ __launch_bounds__(256) void finalize_h(
    const unsigned short* __restrict__ Yh, float* __restrict__ out,
    const float* __restrict__ cptr) {
    const int t = threadIdx.x;
    const int w = t >> 6, l = t & 63;
    const int row0 = blockIdx.x * 8 + w * 2;
    const float c = cptr[0];
    const float rc = sqrtf(c);
    const float maxnorm = (1.0f - 1e-5f) / rc;

    uint4 ha[2], hb[2];
    const uint4* pa = (const uint4*)(Yh + (size_t)row0 * DIM + l * 16);
    const uint4* pb = (const uint4*)(Yh + (size_t)(row0 + 1) * DIM + l * 16);
#pragma unroll
    for (int i = 0; i < 2; ++i) { ha[i] = pa[i]; hb[i] = pb[i]; }

#pragma unroll
    for (int rr = 0; rr < 2; ++rr) {
        const int row = row0 + rr;
        uint4* hv = rr ? hb : ha;
        float y[16];
#pragma unroll
        for (int i = 0; i < 2; ++i) {
            const unsigned int* u = (const unsigned int*)&hv[i];
#pragma unroll
            for (int k = 0; k < 4; ++k) {
                y[i * 8 + k * 2]     = __half2float(__ushort_as_half((unsigned short)(u[k] & 0xffff)));
                y[i * 8 + k * 2 + 1] = __half2float(__ushort_as_half((unsigned short)(u[k] >> 16)));
            }
        }
        float s1 = 0.f, s2 = 0.f;
        float r[16];
#pragma unroll
        for (int k = 0; k < 16; ++k) {
            s1 = fmaf(y[k], y[k], s1);
            r[k] = fmaxf(y[k], 0.f);
            s2 = fmaf(r[k], r[k], s2);
        }
#pragma unroll
        for (int off = 32; off > 0; off >>= 1) {
            s1 += __shfl_down(s1, off, 64);
            s2 += __shfl_down(s2, off, 64);
        }
        s1 = __shfl(s1, 0, 64);
        s2 = __shfl(s2, 0, 64);

        float g = 1.0f / (1.0f + sqrtf(1.0f + c * s1));
        float xn = sqrtf(fmaxf(g * g * s1, 1e-15f));
        float arg = fminf(rc * xn, 1.0f - 1e-7f);
        float f1 = atanhf(arg) / (rc * xn);
        float fv = f1 * g;
        float vn = sqrtf(fmaxf(fv * fv * s2, 1e-15f));
        float f2 = tanhf(rc * vn) / (rc * vn);
        float en = sqrtf(fmaxf(f2 * f2 * fv * fv * s2, 1e-15f));
        float pf = (en > maxnorm) ? (maxnorm / en) : 1.0f;
        float zn = sqrtf(fmaxf(pf * pf * f2 * f2 * fv * fv * s2, 1e-15f));
        float arg2 = fminf(rc * zn, 1.0f - 1e-7f);
        float f3 = atanhf(arg2) / (rc * zn);
        float F = f3 * pf * f2 * fv;

        float* op = out + (size_t)row * DIM + l * 16;
#pragma unroll
        for (int i = 0; i < 4; ++i) {
            float4 o = make_float4(F * r[i * 4], F * r[i * 4 + 1],
                                   F * r[i * 4 + 2], F * r[i * 4 + 3]);
            *(float4*)(op + i * 4) = o;
        }
    }
}

extern "C" void kernel_launch(void* const* d_in, const int* in_sizes, int n_in,
                              void* d_out, int out_size, void* d_ws, size_t ws_size,
                              hipStream_t stream) {
    const float* inputs   = (const float*)d_in[0];
    const float* weigh_v  = (const float*)d_in[1];
    const float* weight_g = (const float*)d_in[2];
    const float* bias     = (const float*)d_in[3];
    const float* cptr     = (const float*)d_in[4];
    float* out = (float*)d_out;

    // workspace layout (~66.3 MB)
    char* ws = (char*)d_ws;
    short* Aws = (short*)ws;                                       // 32 MB
    short* Bws = (short*)(ws + (size_t)32 * 1024 * 1024);          // 2 MB
    unsigned short* Yh = (unsigned short*)(ws + (size_t)34 * 1024 * 1024); // 32 MB
    float* cx2  = (float*)(ws + (size_t)66 * 1024 * 1024);         // 64 KB
    float* part = (float*)(ws + (size_t)66 * 1024 * 1024 + 65536); // 64 KB

    prep_fused<<<2048 + 256, 256, 0, stream>>>(inputs, weigh_v, cptr,
                                               Aws, Bws, cx2, part);
    gemm_mfma<<<256, 512, 0, stream>>>(Aws, Bws, cx2, part,
                                       weight_g, bias, cptr, Yh);
    finalize_h<<<2048, 256, 0, stream>>>(Yh, out, cptr);
}